// Round 1
// baseline (510.452 us; speedup 1.0000x reference)
//
#include <hip/hip_runtime.h>
#include <math.h>

// Problem geometry (fixed by the reference):
//   z:     [16, 64, 32, 32] f32  -> N = 16*32*32 = 16384 query vectors of dim 64
//   emb_w: [16384, 64] f32
//   out:   1048576 f32 (z_q in bchw) + 1 f32 (loss)
#define NQ        16384
#define NE        16384
#define DIM       64
#define CS        16                 // code-dimension splits (grid.y of argmin kernel)
#define CPS       (NE / CS)          // 1024 codes per split
#define TC        64                 // codes per LDS tile
#define THREADS   256

// ws layout (f32 words):
//   [0, NE)                     : code norms ||e||^2
//   [NE, NE + CS*NQ)            : partial min value
//   [NE + CS*NQ, NE + 2*CS*NQ)  : partial min index (u32)
//   [NE + 2*CS*NQ, +64)         : per-block loss partials
// total ~2.2 MB

__global__ __launch_bounds__(THREADS)
void vq_norms(const float* __restrict__ emb, float* __restrict__ norms) {
    int e = blockIdx.x * THREADS + threadIdx.x;
    const float4* row = reinterpret_cast<const float4*>(emb + (size_t)e * DIM);
    float s = 0.f;
#pragma unroll
    for (int i = 0; i < DIM / 4; ++i) {
        float4 v = row[i];
        s = fmaf(v.x, v.x, s); s = fmaf(v.y, v.y, s);
        s = fmaf(v.z, v.z, s); s = fmaf(v.w, v.w, s);
    }
    norms[e] = s;
}

// Each thread owns 2 queries (z vectors in registers). Block = 256 threads
// -> 512 queries. Codebook rows staged 64-at-a-time into LDS; all lanes read
// the same row (broadcast ds_read_b128, conflict-free). score = ||e||^2 - 2 z.e
// (the ||z||^2 term is constant per query -> same argmin as the reference).
__global__ __launch_bounds__(THREADS)
void vq_argmin_partial(const float* __restrict__ z,
                       const float* __restrict__ emb,
                       const float* __restrict__ norms,
                       float* __restrict__ pval,
                       unsigned int* __restrict__ pidx) {
    __shared__ float4 se[TC * (DIM / 4)];   // 64 codes x 16 float4 = 16 KB
    __shared__ float  sn[TC];

    const int t     = threadIdx.x;
    const int n0    = blockIdx.x * (2 * THREADS) + t;
    const int n1    = n0 + THREADS;
    const int cbase = blockIdx.y * CPS;

    // Load both query vectors into registers. z[b][c][h][w]: element c of
    // query n is z[(n>>10)*65536 + c*1024 + (n&1023)] -> coalesced across lanes.
    float4 z0[DIM / 4], z1[DIM / 4];
    {
        const float* p0 = z + (size_t)(n0 >> 10) * 65536 + (n0 & 1023);
        const float* p1 = z + (size_t)(n1 >> 10) * 65536 + (n1 & 1023);
#pragma unroll
        for (int c4 = 0; c4 < DIM / 4; ++c4) {
            z0[c4].x = p0[(c4 * 4 + 0) * 1024];
            z0[c4].y = p0[(c4 * 4 + 1) * 1024];
            z0[c4].z = p0[(c4 * 4 + 2) * 1024];
            z0[c4].w = p0[(c4 * 4 + 3) * 1024];
            z1[c4].x = p1[(c4 * 4 + 0) * 1024];
            z1[c4].y = p1[(c4 * 4 + 1) * 1024];
            z1[c4].z = p1[(c4 * 4 + 2) * 1024];
            z1[c4].w = p1[(c4 * 4 + 3) * 1024];
        }
    }

    float m0 = INFINITY, m1 = INFINITY;
    unsigned int i0 = 0u, i1 = 0u;

    for (int tile = 0; tile < CPS; tile += TC) {
        // Stage 64 contiguous codebook rows (16 KB, fully coalesced).
        const float4* src = reinterpret_cast<const float4*>(
            emb + (size_t)(cbase + tile) * DIM);
#pragma unroll
        for (int k = 0; k < (TC * DIM / 4) / THREADS; ++k)
            se[t + k * THREADS] = src[t + k * THREADS];
        if (t < TC) sn[t] = norms[cbase + tile + t];
        __syncthreads();

#pragma unroll 2
        for (int j = 0; j < TC; ++j) {
            const float4* ev = &se[j * (DIM / 4)];
            float4 a0 = {0.f, 0.f, 0.f, 0.f};
            float4 a1 = {0.f, 0.f, 0.f, 0.f};
#pragma unroll
            for (int c4 = 0; c4 < DIM / 4; ++c4) {
                float4 e4 = ev[c4];   // uniform address -> LDS broadcast
                a0.x = fmaf(e4.x, z0[c4].x, a0.x);
                a0.y = fmaf(e4.y, z0[c4].y, a0.y);
                a0.z = fmaf(e4.z, z0[c4].z, a0.z);
                a0.w = fmaf(e4.w, z0[c4].w, a0.w);
                a1.x = fmaf(e4.x, z1[c4].x, a1.x);
                a1.y = fmaf(e4.y, z1[c4].y, a1.y);
                a1.z = fmaf(e4.z, z1[c4].z, a1.z);
                a1.w = fmaf(e4.w, z1[c4].w, a1.w);
            }
            float d0 = (a0.x + a0.y) + (a0.z + a0.w);
            float d1 = (a1.x + a1.y) + (a1.z + a1.w);
            float s0 = fmaf(-2.f, d0, sn[j]);
            float s1 = fmaf(-2.f, d1, sn[j]);
            unsigned int code = (unsigned int)(cbase + tile + j);
            if (s0 < m0) { m0 = s0; i0 = code; }   // strict < : first-min ties
            if (s1 < m1) { m1 = s1; i1 = code; }
        }
        __syncthreads();
    }

    pval[(size_t)blockIdx.y * NQ + n0] = m0;
    pval[(size_t)blockIdx.y * NQ + n1] = m1;
    pidx[(size_t)blockIdx.y * NQ + n0] = i0;
    pidx[(size_t)blockIdx.y * NQ + n1] = i1;
}

// Reduce the CS partials per query (ascending split id, strict < -> matches
// jnp.argmin first-min), gather the winning embedding row, write bchw output
// (coalesced: for fixed c, consecutive lanes hit consecutive addresses),
// and accumulate the commitment-loss partial per block (deterministic).
__global__ __launch_bounds__(THREADS)
void vq_finalize(const float* __restrict__ z,
                 const float* __restrict__ emb,
                 const float* __restrict__ pval,
                 const unsigned int* __restrict__ pidx,
                 float* __restrict__ out,
                 float* __restrict__ lossp) {
    const int t = threadIdx.x;
    const int n = blockIdx.x * THREADS + t;

    float best = INFINITY;
    unsigned int bi = 0u;
#pragma unroll
    for (int s = 0; s < CS; ++s) {
        float v = pval[(size_t)s * NQ + n];
        unsigned int ix = pidx[(size_t)s * NQ + n];
        if (v < best) { best = v; bi = ix; }
    }

    const float4* er = reinterpret_cast<const float4*>(emb + (size_t)bi * DIM);
    const float* zp = z   + (size_t)(n >> 10) * 65536 + (n & 1023);
    float*       op = out + (size_t)(n >> 10) * 65536 + (n & 1023);

    float ls = 0.f;
#pragma unroll
    for (int c4 = 0; c4 < DIM / 4; ++c4) {
        float4 e4 = er[c4];
        float zv, d;
        zv = zp[(c4 * 4 + 0) * 1024]; op[(c4 * 4 + 0) * 1024] = e4.x; d = e4.x - zv; ls = fmaf(d, d, ls);
        zv = zp[(c4 * 4 + 1) * 1024]; op[(c4 * 4 + 1) * 1024] = e4.y; d = e4.y - zv; ls = fmaf(d, d, ls);
        zv = zp[(c4 * 4 + 2) * 1024]; op[(c4 * 4 + 2) * 1024] = e4.z; d = e4.z - zv; ls = fmaf(d, d, ls);
        zv = zp[(c4 * 4 + 3) * 1024]; op[(c4 * 4 + 3) * 1024] = e4.w; d = e4.w - zv; ls = fmaf(d, d, ls);
    }

    // wave (64-lane) + block reduction of the loss partial
#pragma unroll
    for (int off = 32; off > 0; off >>= 1) ls += __shfl_down(ls, off, 64);
    __shared__ float wsum[THREADS / 64];
    if ((t & 63) == 0) wsum[t >> 6] = ls;
    __syncthreads();
    if (t == 0) {
        float s = 0.f;
#pragma unroll
        for (int w = 0; w < THREADS / 64; ++w) s += wsum[w];
        lossp[blockIdx.x] = s;
    }
}

__global__ __launch_bounds__(64)
void vq_loss_final(const float* __restrict__ lossp, float* __restrict__ out) {
    float v = lossp[threadIdx.x];
#pragma unroll
    for (int off = 32; off > 0; off >>= 1) v += __shfl_down(v, off, 64);
    if (threadIdx.x == 0)
        out[1048576] = 0.25f * v / 1048576.0f;   // BETA * mean
}

extern "C" void kernel_launch(void* const* d_in, const int* in_sizes, int n_in,
                              void* d_out, int out_size, void* d_ws, size_t ws_size,
                              hipStream_t stream) {
    const float* z   = (const float*)d_in[0];
    const float* emb = (const float*)d_in[1];
    float* out = (float*)d_out;

    float* ws = (float*)d_ws;
    float*        norms = ws;
    float*        pval  = ws + NE;
    unsigned int* pidx  = (unsigned int*)(ws + NE + (size_t)CS * NQ);
    float*        lossp = ws + NE + 2 * (size_t)CS * NQ;

    vq_norms<<<NE / THREADS, THREADS, 0, stream>>>(emb, norms);

    dim3 gridB(NQ / (2 * THREADS), CS);   // 32 x 16 = 512 blocks
    vq_argmin_partial<<<gridB, THREADS, 0, stream>>>(z, emb, norms, pval, pidx);

    vq_finalize<<<NQ / THREADS, THREADS, 0, stream>>>(z, emb, pval, pidx, out, lossp);

    vq_loss_final<<<1, 64, 0, stream>>>(lossp, out);
}

// Round 2
// 128.844 us; speedup vs baseline: 3.9618x; 3.9618x over previous
//
#include <hip/hip_runtime.h>
#include <math.h>

// z:     [16, 64, 32, 32] f32 -> N = 16384 queries of dim 64
// emb_w: [16384, 64] f32
// out:   1048576 f32 (z_q bchw) + 1 f32 (loss)
#define NQ      16384
#define NE      16384
#define DIM     64
#define SPLITS  8
#define CPS     (NE / SPLITS)     // 2048 codes per split
#define NT      64                // codes per LDS tile
#define NTILES  (CPS / NT)        // 32
#define THREADS 256

typedef _Float16 half8 __attribute__((ext_vector_type(8)));
typedef float    f32x4 __attribute__((ext_vector_type(4)));
typedef unsigned int uint32;

// ---------------- ws layout (f32 words) ----------------
// norms  @ 0            [16384]
// pval   @ 16384        [8*16384]
// pidx   @ 147456       [8*16384] (u32)
// lossp  @ 278528       [64]
// zh1    @ 278592       [16384*64 halves = 524288 words]  (-2*z hi)
// zh2    @ 802880       [524288]                          (-2*z lo)
// eh1    @ 1327168      [524288]                          (emb hi)
// eh2    @ 1851456      [524288]                          (emb lo)
// total ~9.1 MB

// Split emb rows into fp16 hi/lo and compute ||e||^2 (fp32).
__global__ __launch_bounds__(THREADS)
void prep_emb(const float* __restrict__ emb, _Float16* __restrict__ eh1,
              _Float16* __restrict__ eh2, float* __restrict__ norms) {
    int e = blockIdx.x * THREADS + threadIdx.x;
    const float4* row = reinterpret_cast<const float4*>(emb + (size_t)e * DIM);
    float s = 0.f;
#pragma unroll
    for (int i = 0; i < DIM / 4; ++i) {
        float4 v = row[i];
        s = fmaf(v.x, v.x, s); s = fmaf(v.y, v.y, s);
        s = fmaf(v.z, v.z, s); s = fmaf(v.w, v.w, s);
        union { _Float16 h[4]; uint2 u; } p1, p2;
        float f[4] = {v.x, v.y, v.z, v.w};
#pragma unroll
        for (int j = 0; j < 4; ++j) {
            _Float16 h1 = (_Float16)f[j];
            p1.h[j] = h1;
            p2.h[j] = (_Float16)(f[j] - (float)h1);
        }
        *reinterpret_cast<uint2*>(eh1 + (size_t)e * DIM + i * 4) = p1.u;
        *reinterpret_cast<uint2*>(eh2 + (size_t)e * DIM + i * 4) = p2.u;
    }
    norms[e] = s;
}

// Gather query n from bchw z, scale by -2, split to fp16 hi/lo, store row-major.
__global__ __launch_bounds__(THREADS)
void prep_z(const float* __restrict__ z, _Float16* __restrict__ zh1,
            _Float16* __restrict__ zh2) {
    int n = blockIdx.x * THREADS + threadIdx.x;
    const float* zp = z + (size_t)(n >> 10) * 65536 + (n & 1023);
#pragma unroll 8
    for (int c = 0; c < DIM; ++c) {
        float x = -2.f * zp[(size_t)c * 1024];     // coalesced across lanes
        _Float16 h1 = (_Float16)x;
        _Float16 h2 = (_Float16)(x - (float)h1);
        zh1[(size_t)n * DIM + c] = h1;
        zh2[(size_t)n * DIM + c] = h2;
    }
}

// Fused fp16x2-split MFMA distance GEMM + running argmin.
// Block = 4 waves x 64 queries (A in regs). Codes staged 64 at a time in LDS
// (16B-slot XOR swizzle kills the stride-128B bank conflict). score =
// ||e||^2 + (-2z).e accumulates in fp32 via 6 MFMAs per 16x16 tile.
__global__ __launch_bounds__(THREADS)
void vq_mfma(const _Float16* __restrict__ zh1, const _Float16* __restrict__ zh2,
             const _Float16* __restrict__ eh1, const _Float16* __restrict__ eh2,
             const float* __restrict__ norms,
             float* __restrict__ pval, uint32* __restrict__ pidx) {
    __shared__ __align__(16) unsigned char smem[NT * DIM * 2 * 2 + NT * 4]; // 16640 B

    const int t    = threadIdx.x;
    const int lane = t & 63;
    const int wave = t >> 6;
    const int qbase = blockIdx.x * 256 + wave * 64;
    const int cbase = blockIdx.y * CPS;
    const int r15 = lane & 15, hk = lane >> 4;

    // A fragments: lane holds row (lane&15), k = kc*32 + (lane>>4)*8 .. +8
    half8 A1[4][2], A2[4][2];
#pragma unroll
    for (int mt = 0; mt < 4; ++mt)
#pragma unroll
        for (int kc = 0; kc < 2; ++kc) {
            size_t off = (size_t)(qbase + mt * 16 + r15) * DIM + kc * 32 + hk * 8;
            A1[mt][kc] = *reinterpret_cast<const half8*>(zh1 + off);
            A2[mt][kc] = *reinterpret_cast<const half8*>(zh2 + off);
        }

    float  mv[16];
    uint32 mi[16];
#pragma unroll
    for (int r = 0; r < 16; ++r) { mv[r] = INFINITY; mi[r] = 0u; }

    f32x4 g1[2], g2[2];
    float gn = 0.f;

#define ISSUE(tile)                                                              \
    {                                                                            \
        const unsigned char* s1 = (const unsigned char*)eh1 +                    \
                                  (size_t)(cbase + (tile) * NT) * 128;           \
        const unsigned char* s2 = (const unsigned char*)eh2 +                    \
                                  (size_t)(cbase + (tile) * NT) * 128;           \
        g1[0] = *(const f32x4*)(s1 + t * 16);                                    \
        g1[1] = *(const f32x4*)(s1 + t * 16 + 4096);                             \
        g2[0] = *(const f32x4*)(s2 + t * 16);                                    \
        g2[1] = *(const f32x4*)(s2 + t * 16 + 4096);                             \
        if (t < NT) gn = norms[cbase + (tile) * NT + t];                         \
    }

    ISSUE(0);

    for (int tile = 0; tile < NTILES; ++tile) {
        __syncthreads();    // previous tile's reads done
        // commit staged regs -> LDS with 16B-slot XOR swizzle (T2)
#pragma unroll
        for (int i = 0; i < 2; ++i) {
            int lin = t * 16 + i * 4096;
            int row = lin >> 7;
            int dst = (lin & ~0x70) | (((lin >> 4) & 7) ^ (row & 7)) << 4;
            *(f32x4*)(smem + dst)        = g1[i];
            *(f32x4*)(smem + 8192 + dst) = g2[i];
        }
        if (t < NT) *(float*)(smem + 16384 + t * 4) = gn;
        __syncthreads();
        if (tile + 1 < NTILES) ISSUE(tile + 1);   // issue-early (T14)

#pragma unroll
        for (int s = 0; s < 4; ++s) {
            const int cr = s * 16 + r15;           // code row within tile
            half8 b1[2], b2[2];
#pragma unroll
            for (int kc = 0; kc < 2; ++kc) {
                int slot = (kc << 2) | hk;
                int addr = cr * 128 + (((slot ^ (cr & 7)) << 4));
                b1[kc] = *reinterpret_cast<const half8*>(smem + addr);
                b2[kc] = *reinterpret_cast<const half8*>(smem + 8192 + addr);
            }
            float  nrm  = *(const float*)(smem + 16384 + cr * 4);  // broadcast
            uint32 code = (uint32)(cbase + tile * NT + s * 16 + r15);
#pragma unroll
            for (int mt = 0; mt < 4; ++mt) {
                f32x4 acc = {0.f, 0.f, 0.f, 0.f};
                acc = __builtin_amdgcn_mfma_f32_16x16x32_f16(A1[mt][0], b1[0], acc, 0, 0, 0);
                acc = __builtin_amdgcn_mfma_f32_16x16x32_f16(A1[mt][1], b1[1], acc, 0, 0, 0);
                acc = __builtin_amdgcn_mfma_f32_16x16x32_f16(A1[mt][0], b2[0], acc, 0, 0, 0);
                acc = __builtin_amdgcn_mfma_f32_16x16x32_f16(A1[mt][1], b2[1], acc, 0, 0, 0);
                acc = __builtin_amdgcn_mfma_f32_16x16x32_f16(A2[mt][0], b1[0], acc, 0, 0, 0);
                acc = __builtin_amdgcn_mfma_f32_16x16x32_f16(A2[mt][1], b1[1], acc, 0, 0, 0);
#pragma unroll
                for (int i = 0; i < 4; ++i) {
                    float sv = acc[i] + nrm;
                    int r = mt * 4 + i;
                    if (sv < mv[r]) { mv[r] = sv; mi[r] = code; }  // first-min
                }
            }
        }
    }

    // reduce across the 16 code-columns (lanes within each 16-group),
    // tie -> lower code index (matches jnp.argmin first-min).
#pragma unroll
    for (int st = 1; st < 16; st <<= 1) {
#pragma unroll
        for (int r = 0; r < 16; ++r) {
            float  ov = __shfl_xor(mv[r], st, 64);
            uint32 oi = (uint32)__shfl_xor((int)mi[r], st, 64);
            if (ov < mv[r] || (ov == mv[r] && oi < mi[r])) { mv[r] = ov; mi[r] = oi; }
        }
    }
    if ((lane & 15) == 0) {
#pragma unroll
        for (int mt = 0; mt < 4; ++mt)
#pragma unroll
            for (int i = 0; i < 4; ++i) {
                int q = qbase + mt * 16 + hk * 4 + i;   // C/D row mapping
                pval[(size_t)blockIdx.y * NQ + q] = mv[mt * 4 + i];
                pidx[(size_t)blockIdx.y * NQ + q] = mi[mt * 4 + i];
            }
    }
#undef ISSUE
}

// Reduce the SPLITS partials per query (ascending split -> first-min), gather
// winning emb row, write bchw output, per-block deterministic loss partial.
__global__ __launch_bounds__(THREADS)
void vq_finalize(const float* __restrict__ z,
                 const float* __restrict__ emb,
                 const float* __restrict__ pval,
                 const uint32* __restrict__ pidx,
                 float* __restrict__ out,
                 float* __restrict__ lossp) {
    const int t = threadIdx.x;
    const int n = blockIdx.x * THREADS + t;

    float best = INFINITY;
    uint32 bi = 0u;
#pragma unroll
    for (int s = 0; s < SPLITS; ++s) {
        float v = pval[(size_t)s * NQ + n];
        uint32 ix = pidx[(size_t)s * NQ + n];
        if (v < best) { best = v; bi = ix; }
    }

    const float4* er = reinterpret_cast<const float4*>(emb + (size_t)bi * DIM);
    const float* zp = z   + (size_t)(n >> 10) * 65536 + (n & 1023);
    float*       op = out + (size_t)(n >> 10) * 65536 + (n & 1023);

    float ls = 0.f;
#pragma unroll
    for (int c4 = 0; c4 < DIM / 4; ++c4) {
        float4 e4 = er[c4];
        float zv, d;
        zv = zp[(c4 * 4 + 0) * 1024]; op[(c4 * 4 + 0) * 1024] = e4.x; d = e4.x - zv; ls = fmaf(d, d, ls);
        zv = zp[(c4 * 4 + 1) * 1024]; op[(c4 * 4 + 1) * 1024] = e4.y; d = e4.y - zv; ls = fmaf(d, d, ls);
        zv = zp[(c4 * 4 + 2) * 1024]; op[(c4 * 4 + 2) * 1024] = e4.z; d = e4.z - zv; ls = fmaf(d, d, ls);
        zv = zp[(c4 * 4 + 3) * 1024]; op[(c4 * 4 + 3) * 1024] = e4.w; d = e4.w - zv; ls = fmaf(d, d, ls);
    }

#pragma unroll
    for (int off = 32; off > 0; off >>= 1) ls += __shfl_down(ls, off, 64);
    __shared__ float wsum[THREADS / 64];
    if ((t & 63) == 0) wsum[t >> 6] = ls;
    __syncthreads();
    if (t == 0) {
        float s = 0.f;
#pragma unroll
        for (int w = 0; w < THREADS / 64; ++w) s += wsum[w];
        lossp[blockIdx.x] = s;
    }
}

__global__ __launch_bounds__(64)
void vq_loss_final(const float* __restrict__ lossp, float* __restrict__ out) {
    float v = lossp[threadIdx.x];
#pragma unroll
    for (int off = 32; off > 0; off >>= 1) v += __shfl_down(v, off, 64);
    if (threadIdx.x == 0)
        out[1048576] = 0.25f * v / 1048576.0f;
}

extern "C" void kernel_launch(void* const* d_in, const int* in_sizes, int n_in,
                              void* d_out, int out_size, void* d_ws, size_t ws_size,
                              hipStream_t stream) {
    const float* z   = (const float*)d_in[0];
    const float* emb = (const float*)d_in[1];
    float* out = (float*)d_out;

    float* ws = (float*)d_ws;
    float*     norms = ws;
    float*     pval  = ws + 16384;
    uint32*    pidx  = (uint32*)(ws + 147456);
    float*     lossp = ws + 278528;
    _Float16*  zh1   = (_Float16*)(ws + 278592);
    _Float16*  zh2   = (_Float16*)(ws + 802880);
    _Float16*  eh1   = (_Float16*)(ws + 1327168);
    _Float16*  eh2   = (_Float16*)(ws + 1851456);

    prep_emb<<<NE / THREADS, THREADS, 0, stream>>>(emb, eh1, eh2, norms);
    prep_z<<<NQ / THREADS, THREADS, 0, stream>>>(z, zh1, zh2);

    dim3 grid(NQ / 256, SPLITS);   // 64 x 8 = 512 blocks
    vq_mfma<<<grid, THREADS, 0, stream>>>(zh1, zh2, eh1, eh2, norms, pval, pidx);

    vq_finalize<<<NQ / THREADS, THREADS, 0, stream>>>(z, emb, pval, pidx, out, lossp);
    vq_loss_final<<<1, 64, 0, stream>>>(lossp, out);
}